// Round 2
// baseline (148.529 us; speedup 1.0000x reference)
//
#include <hip/hip_runtime.h>

// LinearAttention fused pipeline, MI355X gfx950.
// k_init:  w_qkv f32 -> wh f16, zero kv/den (no hipMemset)
// k_qkv:   read x[b][c][n] f32 directly; LDS-transpose 64-pixel tile to
//          A[64n][256c] f16 (padded); B-frags gathered from global (L2);
//          q -> elu1 -> qh; k',v reduced in-register -> kv/den atomics.
// k_ws:    ws[b][o][c] = w_out[o][c] * kv/den * 1024  (f16)
// k_gemm2_ln: out2 = ws . qh^T fused with channel LayerNorm -> d_out f32

#define NB 16
#define NC 256
#define NN 4096
#define LN_EPS 1e-5f
#define IOSCALE (1.0f/1024.0f)

typedef _Float16 f16;
typedef _Float16 f16x8 __attribute__((ext_vector_type(8)));
typedef float f32x4 __attribute__((ext_vector_type(4)));

typedef __attribute__((address_space(1))) const unsigned int* as1cu32;
typedef __attribute__((address_space(3))) unsigned int* as3u32;

__device__ __forceinline__ void gload16(const void* g, void* l) {
  __builtin_amdgcn_global_load_lds((as1cu32)g, (as3u32)l, 16, 0, 0);
}

__device__ __forceinline__ float elu1(float x) {
  return x > 0.f ? x + 1.f : __expf(x);
}

__global__ __launch_bounds__(256) void k_init(const float* __restrict__ w,
                                              f16* __restrict__ wh,
                                              float* __restrict__ kvden) {
  int i = blockIdx.x * 256 + threadIdx.x;
  if (i < 768 * 256) wh[i] = (f16)w[i];
  if (i < 8192) kvden[i] = 0.f;
}

// Fused QKV. Block: 64 pixels (n0..n0+64) x all 768 output channels.
// 512 threads = 8 waves; wave = 32n x {q,k,v}[64 channels]; acc 24 f32x4.
__global__ __launch_bounds__(512, 2) void k_qkv(const float* __restrict__ x,
                                                const f16* __restrict__ wh,
                                                f16* __restrict__ qh,
                                                float* __restrict__ kv,
                                                float* __restrict__ den) {
  __shared__ __align__(16) f16 A[64 * 264];   // [n][c], pad 256->264 halves
  const int b = blockIdx.y;
  const int n0 = blockIdx.x * 64;
  const int tid = threadIdx.x;
  const int lane = tid & 63;
  const int wv = tid >> 6;
  const int l15 = lane & 15, lg = lane >> 4;

  // ---- stage: x[b][c][n0:n0+64] f32 -> A[n][c] f16 (transpose) ----
  {
    const int c = tid >> 1;
    const int nh = (tid & 1) * 32;
    const float* xp = x + ((size_t)(b * NC + c)) * NN + n0 + nh;
#pragma unroll
    for (int i = 0; i < 8; ++i) {
      const float4 v4 = *reinterpret_cast<const float4*>(xp + i * 4);
      const int nb = nh + i * 4;
      A[(nb + 0) * 264 + c] = (f16)v4.x;
      A[(nb + 1) * 264 + c] = (f16)v4.y;
      A[(nb + 2) * 264 + c] = (f16)v4.z;
      A[(nb + 3) * 264 + c] = (f16)v4.w;
    }
  }
  __syncthreads();

  const int ng = wv >> 2;          // n-subtile 0..1
  const int cb = (wv & 3) * 64;    // channel base 0/64/128/192

  f32x4 aq[2][4] = {}, ak[2][4] = {}, av[2][4] = {};
  const f16* arow0 = A + (ng * 32 + l15) * 264;
  const f16* arow1 = arow0 + 16 * 264;
  const f16* wl = wh + (size_t)(cb + l15) * NC + lg * 8;

#pragma unroll 2
  for (int kq = 0; kq < 8; ++kq) {
    const int kb = kq * 32 + lg * 8;
    const f16x8 a0 = *(const f16x8*)(arow0 + kb);
    const f16x8 a1 = *(const f16x8*)(arow1 + kb);
#pragma unroll
    for (int f = 0; f < 4; ++f) {
      const f16* wf = wl + f * 16 * NC + kq * 32;
      const f16x8 bq = *(const f16x8*)(wf);
      const f16x8 bk = *(const f16x8*)(wf + 256 * NC);
      const f16x8 bv = *(const f16x8*)(wf + 512 * NC);
      aq[0][f] = __builtin_amdgcn_mfma_f32_16x16x32_f16(a0, bq, aq[0][f], 0, 0, 0);
      aq[1][f] = __builtin_amdgcn_mfma_f32_16x16x32_f16(a1, bq, aq[1][f], 0, 0, 0);
      ak[0][f] = __builtin_amdgcn_mfma_f32_16x16x32_f16(a0, bk, ak[0][f], 0, 0, 0);
      ak[1][f] = __builtin_amdgcn_mfma_f32_16x16x32_f16(a1, bk, ak[1][f], 0, 0, 0);
      av[0][f] = __builtin_amdgcn_mfma_f32_16x16x32_f16(a0, bv, av[0][f], 0, 0, 0);
      av[1][f] = __builtin_amdgcn_mfma_f32_16x16x32_f16(a1, bv, av[1][f], 0, 0, 0);
    }
  }

  // ---- q epilogue: elu1 -> qh[b][n][c] ----
#pragma unroll
  for (int m = 0; m < 2; ++m) {
    const int nr = n0 + ng * 32 + m * 16 + lg * 4;
#pragma unroll
    for (int f = 0; f < 4; ++f) {
      const int oc = cb + f * 16 + l15;
#pragma unroll
      for (int j = 0; j < 4; ++j)
        qh[((size_t)(b * NN + nr + j)) * NC + oc] = (f16)elu1(aq[m][f][j]);
    }
  }

  // ---- kv/den reduction over this wave's 32 pixels ----
  float pkv[4] = {0.f, 0.f, 0.f, 0.f}, pden[4] = {0.f, 0.f, 0.f, 0.f};
#pragma unroll
  for (int f = 0; f < 4; ++f)
#pragma unroll
    for (int m = 0; m < 2; ++m)
#pragma unroll
      for (int j = 0; j < 4; ++j) {
        const float kk = elu1(ak[m][f][j]);
        pkv[f] += kk * av[m][f][j];
        pden[f] += kk;
      }
#pragma unroll
  for (int f = 0; f < 4; ++f) {
    pkv[f] += __shfl_xor(pkv[f], 16, 64);
    pkv[f] += __shfl_xor(pkv[f], 32, 64);
    pden[f] += __shfl_xor(pden[f], 16, 64);
    pden[f] += __shfl_xor(pden[f], 32, 64);
  }
  if (lane < 16) {
#pragma unroll
    for (int f = 0; f < 4; ++f) {
      atomicAdd(&kv[b * NC + cb + f * 16 + lane], pkv[f]);
      atomicAdd(&den[b * NC + cb + f * 16 + lane], pden[f]);
    }
  }
}

__global__ __launch_bounds__(256) void k_ws(const float* __restrict__ wout,
                                            const float* __restrict__ kv,
                                            const float* __restrict__ den,
                                            f16* __restrict__ wsc) {
  int i = blockIdx.x * 256 + threadIdx.x;  // 16*256*256
  int c = i & 255;
  int o = (i >> 8) & 255;
  int b = i >> 16;
  float s = kv[b * 256 + c] / fmaxf(den[b * 256 + c], 1e-6f);
  wsc[i] = (f16)(wout[o * 256 + c] * s * 1024.0f);
}

// D[o][n] = sum_c wsc[b][o][c] * qh[b][n][c]; fused LayerNorm over o per column n.
__global__ __launch_bounds__(256) void k_gemm2_ln(const f16* __restrict__ wsc,
                                                  const f16* __restrict__ qh,
                                                  const float* __restrict__ gamma,
                                                  const float* __restrict__ beta,
                                                  float* __restrict__ out) {
  __shared__ __align__(16) f16 At[256 * 64];
  __shared__ __align__(16) f16 Bt[64 * 64];
  __shared__ float red1[4][64];
  __shared__ float red2[4][64];
  __shared__ float smu[64], srs[64];
  const int b = blockIdx.y;
  const int n0 = blockIdx.x * 64;
  const int tid = threadIdx.x;
  const int lane = tid & 63;
  const int wv = tid >> 6;   // wave owns o rows [wv*64, wv*64+64)
  const int l15 = lane & 15, lg = lane >> 4;
  const int srow = lane >> 3;
  const int sch = (lane & 7) * 8;
  const f16* wsb = wsc + (size_t)b * NC * NC;

  f32x4 acc[4][4] = {};

  for (int ks = 0; ks < 4; ++ks) {
    const int c0 = ks * 64;
#pragma unroll
    for (int it = 0; it < 8; ++it) {
      const int seg = wv * 8 + it;       // 0..31
      const int row = seg * 8 + srow;    // 0..255
      gload16(wsb + (size_t)row * NC + c0 + sch, At + seg * 512);
    }
#pragma unroll
    for (int it = 0; it < 2; ++it) {
      const int seg = wv * 2 + it;       // 0..7
      const int row = seg * 8 + srow;    // 0..63
      gload16(qh + ((size_t)(b * NN + n0 + row)) * NC + c0 + sch, Bt + seg * 512);
    }
    __syncthreads();
#pragma unroll
    for (int kk = 0; kk < 2; ++kk) {
      const int kb = kk * 32 + lg * 8;
      f16x8 af[4], bf[4];
#pragma unroll
      for (int m = 0; m < 4; ++m)
        af[m] = *(const f16x8*)(At + (wv * 64 + m * 16 + l15) * 64 + kb);
#pragma unroll
      for (int f = 0; f < 4; ++f)
        bf[f] = *(const f16x8*)(Bt + (f * 16 + l15) * 64 + kb);
#pragma unroll
      for (int m = 0; m < 4; ++m)
#pragma unroll
        for (int f = 0; f < 4; ++f)
          acc[m][f] = __builtin_amdgcn_mfma_f32_16x16x32_f16(af[m], bf[f], acc[m][f], 0, 0, 0);
    }
    __syncthreads();
  }
  float s1[4] = {0, 0, 0, 0}, s2[4] = {0, 0, 0, 0};
#pragma unroll
  for (int f = 0; f < 4; ++f)
#pragma unroll
    for (int m = 0; m < 4; ++m)
#pragma unroll
      for (int j = 0; j < 4; ++j) {
        const float v = acc[m][f][j];
        s1[f] += v;
        s2[f] += v * v;
      }
#pragma unroll
  for (int f = 0; f < 4; ++f) {
    s1[f] += __shfl_xor(s1[f], 16, 64);
    s1[f] += __shfl_xor(s1[f], 32, 64);
    s2[f] += __shfl_xor(s2[f], 16, 64);
    s2[f] += __shfl_xor(s2[f], 32, 64);
  }
  if (lane < 16) {
#pragma unroll
    for (int f = 0; f < 4; ++f) {
      red1[wv][f * 16 + lane] = s1[f];
      red2[wv][f * 16 + lane] = s2[f];
    }
  }
  __syncthreads();
  if (tid < 64) {
    const float a1 = red1[0][tid] + red1[1][tid] + red1[2][tid] + red1[3][tid];
    const float a2 = red2[0][tid] + red2[1][tid] + red2[2][tid] + red2[3][tid];
    const float mu = a1 * (IOSCALE / 256.f);
    const float e2 = a2 * (IOSCALE * IOSCALE / 256.f);
    smu[tid] = mu;
    srs[tid] = rsqrtf(e2 - mu * mu + LN_EPS);
  }
  __syncthreads();
#pragma unroll
  for (int m = 0; m < 4; ++m) {
    const int ob = wv * 64 + m * 16 + lg * 4;
#pragma unroll
    for (int j = 0; j < 4; ++j) {
      const int o = ob + j;
      const float g = gamma[o], be = beta[o];
#pragma unroll
      for (int f = 0; f < 4; ++f) {
        const int col = f * 16 + l15;
        const float v = acc[m][f][j] * IOSCALE;
        out[((size_t)(b * NC + o)) * NN + n0 + col] = (v - smu[col]) * srs[col] * g + be;
      }
    }
  }
}

extern "C" void kernel_launch(void* const* d_in, const int* in_sizes, int n_in,
                              void* d_out, int out_size, void* d_ws, size_t ws_size,
                              hipStream_t stream) {
  const float* x = (const float*)d_in[0];
  const float* w_qkv = (const float*)d_in[1];
  const float* w_out = (const float*)d_in[2];
  const float* ln_g = (const float*)d_in[3];
  const float* ln_b = (const float*)d_in[4];
  float* out = (float*)d_out;

  char* wsb = (char*)d_ws;
  const size_t OFF_WH = 0;                       // 768*256*2 = 393216
  const size_t OFF_QH = OFF_WH + 393216;         // 32 MiB
  const size_t OFF_KV = OFF_QH + 33554432;       // 16 KiB
  const size_t OFF_DEN = OFF_KV + 16384;         // 16 KiB
  const size_t OFF_WSC = OFF_DEN + 16384;        // 2 MiB

  f16* wh = (f16*)(wsb + OFF_WH);
  f16* qh = (f16*)(wsb + OFF_QH);
  float* kv = (float*)(wsb + OFF_KV);
  float* den = (float*)(wsb + OFF_DEN);
  f16* wsc = (f16*)(wsb + OFF_WSC);

  k_init<<<768, 256, 0, stream>>>(w_qkv, wh, kv);
  k_qkv<<<dim3(64, 16), 512, 0, stream>>>(x, wh, qh, kv, den);
  k_ws<<<4096, 256, 0, stream>>>(w_out, kv, den, wsc);
  k_gemm2_ln<<<dim3(64, 16), 256, 0, stream>>>(wsc, qh, ln_g, ln_b, out);
}

// Round 3
// 95.789 us; speedup vs baseline: 1.5506x; 1.5506x over previous
//
#include <hip/hip_runtime.h>

// LinearAttention fused pipeline, MI355X gfx950. Round 3.
// k_init:      w_qkv f32 -> wh f16; zero kv/den (no hipMemset -> no 40us stall)
// k_transpose: x[b][c][n] f32 -> xh[b][n][c] f16 (padded-LDS 64x64 tiles)
// k_gemm_q:    qh = elu1(xh . Wq^T)   128x128 tiles, LDS XOR-swizzled
// k_gemm_kv:   kv/den in-register reduction, 128n x (64k||64v), swizzled
// k_ws:        ws[b][o][c] = w_out[o][c] * kv/den * 1024 (f16)
// k_gemm2_ln:  out = LN(ws . qh^T) fused, swizzled

#define NB 16
#define NC 256
#define NN 4096
#define LN_EPS 1e-5f
#define IOSCALE (1.0f/1024.0f)

typedef _Float16 f16;
typedef _Float16 f16x8 __attribute__((ext_vector_type(8)));
typedef _Float16 f16x4v __attribute__((ext_vector_type(4)));
typedef float f32x4 __attribute__((ext_vector_type(4)));

typedef __attribute__((address_space(1))) const unsigned int* as1cu32;
typedef __attribute__((address_space(3))) unsigned int* as3u32;

__device__ __forceinline__ void gload16(const void* g, void* l) {
  __builtin_amdgcn_global_load_lds((as1cu32)g, (as3u32)l, 16, 0, 0);
}

__device__ __forceinline__ float elu1(float x) {
  return x > 0.f ? x + 1.f : __expf(x);
}

// Swizzled fragment address (halves) within a [rows][64]-f16 LDS tile:
// 16B unit u of row r lives at physical unit u^(r&7). Conflict-free b128 reads.
__device__ __forceinline__ int swz(int row, int unit) {
  return row * 64 + (((unit) ^ (row & 7)) << 3);
}

__global__ __launch_bounds__(256) void k_init(const float* __restrict__ w,
                                              f16* __restrict__ wh,
                                              float* __restrict__ kvden) {
  int i = blockIdx.x * 256 + threadIdx.x;
  if (i < 768 * 256) wh[i] = (f16)w[i];
  if (i < 8192) kvden[i] = 0.f;
}

// x[b][c][n] f32 -> xh[b][n][c] f16. 64x64 tiles via padded LDS.
__global__ __launch_bounds__(256) void k_transpose(const float* __restrict__ x,
                                                   f16* __restrict__ xh) {
  __shared__ float t[64 * 65];
  const int b = blockIdx.z, c0 = blockIdx.y * 64, n0 = blockIdx.x * 64;
  const int tid = threadIdx.x;
#pragma unroll
  for (int i = 0; i < 4; ++i) {
    int lin = tid + i * 256;
    int r = lin >> 4;
    int cg = lin & 15;
    const float4 v = *reinterpret_cast<const float4*>(
        &x[((size_t)(b * NC + c0 + r)) * NN + n0 + cg * 4]);
    t[r * 65 + cg * 4 + 0] = v.x;
    t[r * 65 + cg * 4 + 1] = v.y;
    t[r * 65 + cg * 4 + 2] = v.z;
    t[r * 65 + cg * 4 + 3] = v.w;
  }
  __syncthreads();
#pragma unroll
  for (int i = 0; i < 4; ++i) {
    int lin = tid + i * 256;
    int nr = lin >> 4;
    int cg = lin & 15;
    f16x4v h;
    h[0] = (f16)t[(cg * 4 + 0) * 65 + nr];
    h[1] = (f16)t[(cg * 4 + 1) * 65 + nr];
    h[2] = (f16)t[(cg * 4 + 2) * 65 + nr];
    h[3] = (f16)t[(cg * 4 + 3) * 65 + nr];
    *reinterpret_cast<f16x4v*>(&xh[((size_t)(b * NN + n0 + nr)) * NC + c0 + cg * 4]) = h;
  }
}

// D[n][o] = sum_c xh[n][c] * wh[o][c]; elu+1 -> qh[b][n][o].
__global__ __launch_bounds__(256) void k_gemm_q(const f16* __restrict__ xh,
                                                const f16* __restrict__ wh,
                                                f16* __restrict__ qh) {
  __shared__ __align__(16) f16 At[128 * 64];
  __shared__ __align__(16) f16 Bt[128 * 64];
  const int b = blockIdx.z;
  const int n0 = blockIdx.x * 128;
  const int o0 = blockIdx.y * 128;
  const int tid = threadIdx.x;
  const int lane = tid & 63;
  const int wv = tid >> 6;
  const int wn = wv >> 1, wo = wv & 1;
  const int l15 = lane & 15, lg = lane >> 4;
  const int srow = lane >> 3;              // LDS row within 8-row segment
  const int ssrc = ((lane & 7) ^ srow) * 8;  // pre-swizzled source col (halves)

  f32x4 acc[4][4] = {};

  for (int ks = 0; ks < 4; ++ks) {
    const int c0 = ks * 64;
#pragma unroll
    for (int it = 0; it < 4; ++it) {
      const int seg = wv * 4 + it;
      const int row = seg * 8 + srow;
      gload16(xh + ((size_t)(b * NN + n0 + row)) * NC + c0 + ssrc, At + seg * 512);
      gload16(wh + (size_t)(o0 + row) * NC + c0 + ssrc, Bt + seg * 512);
    }
    __syncthreads();
#pragma unroll
    for (int kk = 0; kk < 2; ++kk) {
      const int ku = kk * 4 + lg;          // 16B k-unit 0..7
      f16x8 af[4], bf[4];
#pragma unroll
      for (int m = 0; m < 4; ++m)
        af[m] = *(const f16x8*)(At + swz(wn * 64 + m * 16 + l15, ku));
#pragma unroll
      for (int n = 0; n < 4; ++n)
        bf[n] = *(const f16x8*)(Bt + swz(wo * 64 + n * 16 + l15, ku));
#pragma unroll
      for (int m = 0; m < 4; ++m)
#pragma unroll
        for (int n = 0; n < 4; ++n)
          acc[m][n] = __builtin_amdgcn_mfma_f32_16x16x32_f16(af[m], bf[n], acc[m][n], 0, 0, 0);
    }
    __syncthreads();
  }
#pragma unroll
  for (int m = 0; m < 4; ++m) {
    const int nr = n0 + wn * 64 + m * 16 + lg * 4;
#pragma unroll
    for (int n = 0; n < 4; ++n) {
      const int oc = o0 + wo * 64 + n * 16 + l15;
#pragma unroll
      for (int j = 0; j < 4; ++j)
        qh[((size_t)(b * NN + nr + j)) * NC + oc] = (f16)elu1(acc[m][n][j]);
    }
  }
}

// k' = elu1(xh.Wk^T), v = xh.Wv^T; reduce kv += k'*v, den += k' over n.
// Tile: 128n x 128 cols (cols 0..63 = k channels cc0.., 64..127 = v same channels).
__global__ __launch_bounds__(256) void k_gemm_kv(const f16* __restrict__ xh,
                                                 const f16* __restrict__ wh,
                                                 float* __restrict__ kv,
                                                 float* __restrict__ den) {
  __shared__ __align__(16) f16 At[128 * 64];
  __shared__ __align__(16) f16 Bt[128 * 64];
  const int b = blockIdx.z;
  const int n0 = blockIdx.x * 128;
  const int cc0 = blockIdx.y * 64;
  const int tid = threadIdx.x;
  const int lane = tid & 63;
  const int wv = tid >> 6;
  const int l15 = lane & 15, lg = lane >> 4;
  const int srow = lane >> 3;
  const int ssrc = ((lane & 7) ^ srow) * 8;

  f32x4 acc[2][8] = {};

  for (int ks = 0; ks < 4; ++ks) {
    const int c0 = ks * 64;
#pragma unroll
    for (int it = 0; it < 4; ++it) {
      const int seg = wv * 4 + it;
      const int row = seg * 8 + srow;
      gload16(xh + ((size_t)(b * NN + n0 + row)) * NC + c0 + ssrc, At + seg * 512);
      const int wrow = row < 64 ? 256 + cc0 + row : 512 + cc0 + (row - 64);
      gload16(wh + (size_t)wrow * NC + c0 + ssrc, Bt + seg * 512);
    }
    __syncthreads();
#pragma unroll
    for (int kk = 0; kk < 2; ++kk) {
      const int ku = kk * 4 + lg;
      f16x8 af[2], bf[8];
#pragma unroll
      for (int m = 0; m < 2; ++m)
        af[m] = *(const f16x8*)(At + swz(wv * 32 + m * 16 + l15, ku));
#pragma unroll
      for (int f = 0; f < 8; ++f)
        bf[f] = *(const f16x8*)(Bt + swz(f * 16 + l15, ku));
#pragma unroll
      for (int m = 0; m < 2; ++m)
#pragma unroll
        for (int f = 0; f < 8; ++f)
          acc[m][f] = __builtin_amdgcn_mfma_f32_16x16x32_f16(af[m], bf[f], acc[m][f], 0, 0, 0);
    }
    __syncthreads();
  }
  float pkv[4] = {0.f, 0.f, 0.f, 0.f}, pden[4] = {0.f, 0.f, 0.f, 0.f};
#pragma unroll
  for (int f = 0; f < 4; ++f)
#pragma unroll
    for (int m = 0; m < 2; ++m)
#pragma unroll
      for (int j = 0; j < 4; ++j) {
        const float kk = elu1(acc[m][f][j]);
        pkv[f] += kk * acc[m][f + 4][j];
        pden[f] += kk;
      }
#pragma unroll
  for (int f = 0; f < 4; ++f) {
    pkv[f] += __shfl_xor(pkv[f], 16, 64);
    pkv[f] += __shfl_xor(pkv[f], 32, 64);
    pden[f] += __shfl_xor(pden[f], 16, 64);
    pden[f] += __shfl_xor(pden[f], 32, 64);
  }
  if (lane < 16) {
#pragma unroll
    for (int f = 0; f < 4; ++f) {
      const int c = cc0 + f * 16 + lane;
      atomicAdd(&kv[b * NC + c], pkv[f]);
      atomicAdd(&den[b * NC + c], pden[f]);
    }
  }
}

__global__ __launch_bounds__(256) void k_ws(const float* __restrict__ wout,
                                            const float* __restrict__ kv,
                                            const float* __restrict__ den,
                                            f16* __restrict__ wsc) {
  int i = blockIdx.x * 256 + threadIdx.x;  // 16*256*256
  int c = i & 255;
  int o = (i >> 8) & 255;
  int b = i >> 16;
  float s = kv[b * 256 + c] / fmaxf(den[b * 256 + c], 1e-6f);
  wsc[i] = (f16)(wout[o * 256 + c] * s * 1024.0f);
}

// D[o][n] = sum_c wsc[b][o][c] * qh[b][n][c]; fused LayerNorm over o per column n.
__global__ __launch_bounds__(256) void k_gemm2_ln(const f16* __restrict__ wsc,
                                                  const f16* __restrict__ qh,
                                                  const float* __restrict__ gamma,
                                                  const float* __restrict__ beta,
                                                  float* __restrict__ out) {
  __shared__ __align__(16) f16 At[256 * 64];
  __shared__ __align__(16) f16 Bt[64 * 64];
  __shared__ float red1[4][64];
  __shared__ float red2[4][64];
  __shared__ float smu[64], srs[64];
  const int b = blockIdx.y;
  const int n0 = blockIdx.x * 64;
  const int tid = threadIdx.x;
  const int lane = tid & 63;
  const int wv = tid >> 6;   // wave owns o rows [wv*64, wv*64+64)
  const int l15 = lane & 15, lg = lane >> 4;
  const int srow = lane >> 3;
  const int ssrc = ((lane & 7) ^ srow) * 8;
  const f16* wsb = wsc + (size_t)b * NC * NC;

  f32x4 acc[4][4] = {};

  for (int ks = 0; ks < 4; ++ks) {
    const int c0 = ks * 64;
#pragma unroll
    for (int it = 0; it < 8; ++it) {
      const int seg = wv * 8 + it;       // 0..31
      const int row = seg * 8 + srow;    // 0..255
      gload16(wsb + (size_t)row * NC + c0 + ssrc, At + seg * 512);
    }
#pragma unroll
    for (int it = 0; it < 2; ++it) {
      const int seg = wv * 2 + it;       // 0..7
      const int row = seg * 8 + srow;    // 0..63
      gload16(qh + ((size_t)(b * NN + n0 + row)) * NC + c0 + ssrc, Bt + seg * 512);
    }
    __syncthreads();
#pragma unroll
    for (int kk = 0; kk < 2; ++kk) {
      const int ku = kk * 4 + lg;
      f16x8 af[4], bf[4];
#pragma unroll
      for (int m = 0; m < 4; ++m)
        af[m] = *(const f16x8*)(At + swz(wv * 64 + m * 16 + l15, ku));
#pragma unroll
      for (int f = 0; f < 4; ++f)
        bf[f] = *(const f16x8*)(Bt + swz(f * 16 + l15, ku));
#pragma unroll
      for (int m = 0; m < 4; ++m)
#pragma unroll
        for (int f = 0; f < 4; ++f)
          acc[m][f] = __builtin_amdgcn_mfma_f32_16x16x32_f16(af[m], bf[f], acc[m][f], 0, 0, 0);
    }
    __syncthreads();
  }
  float s1[4] = {0, 0, 0, 0}, s2[4] = {0, 0, 0, 0};
#pragma unroll
  for (int f = 0; f < 4; ++f)
#pragma unroll
    for (int m = 0; m < 4; ++m)
#pragma unroll
      for (int j = 0; j < 4; ++j) {
        const float v = acc[m][f][j];
        s1[f] += v;
        s2[f] += v * v;
      }
#pragma unroll
  for (int f = 0; f < 4; ++f) {
    s1[f] += __shfl_xor(s1[f], 16, 64);
    s1[f] += __shfl_xor(s1[f], 32, 64);
    s2[f] += __shfl_xor(s2[f], 16, 64);
    s2[f] += __shfl_xor(s2[f], 32, 64);
  }
  if (lane < 16) {
#pragma unroll
    for (int f = 0; f < 4; ++f) {
      red1[wv][f * 16 + lane] = s1[f];
      red2[wv][f * 16 + lane] = s2[f];
    }
  }
  __syncthreads();
  if (tid < 64) {
    const float a1 = red1[0][tid] + red1[1][tid] + red1[2][tid] + red1[3][tid];
    const float a2 = red2[0][tid] + red2[1][tid] + red2[2][tid] + red2[3][tid];
    const float mu = a1 * (IOSCALE / 256.f);
    const float e2 = a2 * (IOSCALE * IOSCALE / 256.f);
    smu[tid] = mu;
    srs[tid] = rsqrtf(e2 - mu * mu + LN_EPS);
  }
  __syncthreads();
#pragma unroll
  for (int m = 0; m < 4; ++m) {
    const int ob = wv * 64 + m * 16 + lg * 4;
#pragma unroll
    for (int j = 0; j < 4; ++j) {
      const int o = ob + j;
      const float g = gamma[o], be = beta[o];
#pragma unroll
      for (int f = 0; f < 4; ++f) {
        const int col = f * 16 + l15;
        const float v = acc[m][f][j] * IOSCALE;
        out[((size_t)(b * NC + o)) * NN + n0 + col] = (v - smu[col]) * srs[col] * g + be;
      }
    }
  }
}

extern "C" void kernel_launch(void* const* d_in, const int* in_sizes, int n_in,
                              void* d_out, int out_size, void* d_ws, size_t ws_size,
                              hipStream_t stream) {
  const float* x = (const float*)d_in[0];
  const float* w_qkv = (const float*)d_in[1];
  const float* w_out = (const float*)d_in[2];
  const float* ln_g = (const float*)d_in[3];
  const float* ln_b = (const float*)d_in[4];
  float* out = (float*)d_out;

  char* wsb = (char*)d_ws;
  const size_t OFF_WH = 0;                       // 768*256*2 = 393216
  const size_t OFF_XH = OFF_WH + 393216;         // 32 MiB
  const size_t OFF_QH = OFF_XH + 33554432;       // 32 MiB
  const size_t OFF_KV = OFF_QH + 33554432;       // 16 KiB (kv) + 16 KiB (den)
  const size_t OFF_DEN = OFF_KV + 16384;
  const size_t OFF_WSC = OFF_DEN + 16384;        // 2 MiB

  f16* wh = (f16*)(wsb + OFF_WH);
  f16* xh = (f16*)(wsb + OFF_XH);
  f16* qh = (f16*)(wsb + OFF_QH);
  float* kv = (float*)(wsb + OFF_KV);
  float* den = (float*)(wsb + OFF_DEN);
  f16* wsc = (f16*)(wsb + OFF_WSC);

  k_init<<<768, 256, 0, stream>>>(w_qkv, wh, kv);
  k_transpose<<<dim3(64, 4, 16), 256, 0, stream>>>(x, xh);
  k_gemm_q<<<dim3(32, 2, 16), 256, 0, stream>>>(xh, wh, qh);
  k_gemm_kv<<<dim3(32, 4, 16), 256, 0, stream>>>(xh, wh, kv, den);
  k_ws<<<4096, 256, 0, stream>>>(w_out, kv, den, wsc);
  k_gemm2_ln<<<dim3(64, 16), 256, 0, stream>>>(wsc, qh, ln_g, ln_b, out);
}

// Round 4
// 84.866 us; speedup vs baseline: 1.7502x; 1.1287x over previous
//
#include <hip/hip_runtime.h>

// LinearAttention fused pipeline, MI355X gfx950. Round 4.
// k_init:      w_qkv->wh f16, w_out->wouth f16, zero kv/den
// k_transpose: x[b][c][n] f32 -> xh[b][n][c] f16
// k_kv:        kv[b][c]=sum_n elu1(k)*v, den=sum elu1(k); xh read ONCE,
//              two B-sweeps (Wk,Wv) through one 32KB LDS buffer
// k_fused2:    qT = Wq.xhT (GEMM) -> elu1*s*1024 -> Q-LDS -> out = wouth.Q
//              (GEMM) -> fused LayerNorm -> d_out. No qh/wsc buffers.

#define NB 16
#define NC 256
#define NN 4096
#define LN_EPS 1e-5f
#define IOSCALE (1.0f/1024.0f)

typedef _Float16 f16;
typedef _Float16 f16x8 __attribute__((ext_vector_type(8)));
typedef _Float16 f16x4v __attribute__((ext_vector_type(4)));
typedef float f32x4 __attribute__((ext_vector_type(4)));

typedef __attribute__((address_space(1))) const unsigned int* as1cu32;
typedef __attribute__((address_space(3))) unsigned int* as3u32;

__device__ __forceinline__ void gload16(const void* g, void* l) {
  __builtin_amdgcn_global_load_lds((as1cu32)g, (as3u32)l, 16, 0, 0);
}

__device__ __forceinline__ float elu1(float x) {
  return x > 0.f ? x + 1.f : __expf(x);
}

// Swizzled fragment address (halves) in a [rows][64]-f16 LDS tile.
__device__ __forceinline__ int swz(int row, int unit) {
  return row * 64 + (((unit) ^ (row & 7)) << 3);
}

__global__ __launch_bounds__(256) void k_init(const float* __restrict__ wqkv,
                                              const float* __restrict__ wout,
                                              f16* __restrict__ wh,
                                              f16* __restrict__ wouth,
                                              float* __restrict__ kvden) {
  int i = blockIdx.x * 256 + threadIdx.x;   // grid covers 768*256 exactly
  wh[i] = (f16)wqkv[i];
  if (i < 65536) wouth[i] = (f16)wout[i];
  if (i < 8192) kvden[i] = 0.f;
}

// x[b][c][n] f32 -> xh[b][n][c] f16. 64x64 tiles via padded LDS.
__global__ __launch_bounds__(256) void k_transpose(const float* __restrict__ x,
                                                   f16* __restrict__ xh) {
  __shared__ float t[64 * 65];
  const int b = blockIdx.z, c0 = blockIdx.y * 64, n0 = blockIdx.x * 64;
  const int tid = threadIdx.x;
#pragma unroll
  for (int i = 0; i < 4; ++i) {
    int lin = tid + i * 256;
    int r = lin >> 4;
    int cg = lin & 15;
    const float4 v = *reinterpret_cast<const float4*>(
        &x[((size_t)(b * NC + c0 + r)) * NN + n0 + cg * 4]);
    t[r * 65 + cg * 4 + 0] = v.x;
    t[r * 65 + cg * 4 + 1] = v.y;
    t[r * 65 + cg * 4 + 2] = v.z;
    t[r * 65 + cg * 4 + 3] = v.w;
  }
  __syncthreads();
#pragma unroll
  for (int i = 0; i < 4; ++i) {
    int lin = tid + i * 256;
    int nr = lin >> 4;
    int cg = lin & 15;
    f16x4v h;
    h[0] = (f16)t[(cg * 4 + 0) * 65 + nr];
    h[1] = (f16)t[(cg * 4 + 1) * 65 + nr];
    h[2] = (f16)t[(cg * 4 + 2) * 65 + nr];
    h[3] = (f16)t[(cg * 4 + 3) * 65 + nr];
    *reinterpret_cast<f16x4v*>(&xh[((size_t)(b * NN + n0 + nr)) * NC + c0 + cg * 4]) = h;
  }
}

// kv/den reduction. Block: 64 pixels x all 256 channels (k AND v).
// 512 threads = 8 waves = 2 n-groups x 4 channel-groups.
__global__ __launch_bounds__(512) void k_kv(const f16* __restrict__ xh,
                                            const f16* __restrict__ wh,
                                            float* __restrict__ kv,
                                            float* __restrict__ den) {
  __shared__ __align__(16) f16 Xt[64 * 64];    // 8 KB
  __shared__ __align__(16) f16 Bt[256 * 64];   // 32 KB (Wk then Wv)
  const int b = blockIdx.y;
  const int n0 = blockIdx.x * 64;
  const int tid = threadIdx.x;
  const int lane = tid & 63;
  const int wv = tid >> 6;          // 0..7
  const int ng = wv >> 2;           // n-subtile (32n)
  const int cg = wv & 3;            // channel group (64ch)
  const int l15 = lane & 15, lg = lane >> 4;
  const int lr = lane >> 3;         // row within 8-row segment
  const int ssrc = ((lane & 7) ^ lr) * 8;

  f32x4 kacc[2][4] = {};
  f32x4 vacc[2][4] = {};

  for (int ks = 0; ks < 4; ++ks) {
    const int c0 = ks * 64;
    __syncthreads();
    gload16(xh + ((size_t)(b * NN + n0 + wv * 8 + lr)) * NC + c0 + ssrc, Xt + wv * 512);
#pragma unroll
    for (int it = 0; it < 4; ++it) {
      const int seg = wv * 4 + it;
      gload16(wh + (size_t)(256 + seg * 8 + lr) * NC + c0 + ssrc, Bt + seg * 512);
    }
    __syncthreads();
#pragma unroll
    for (int kk = 0; kk < 2; ++kk) {
      const int ku = kk * 4 + lg;
      f16x8 af[2], bf[4];
#pragma unroll
      for (int m = 0; m < 2; ++m)
        af[m] = *(const f16x8*)(Xt + swz(ng * 32 + m * 16 + l15, ku));
#pragma unroll
      for (int f = 0; f < 4; ++f)
        bf[f] = *(const f16x8*)(Bt + swz(cg * 64 + f * 16 + l15, ku));
#pragma unroll
      for (int m = 0; m < 2; ++m)
#pragma unroll
        for (int f = 0; f < 4; ++f)
          kacc[m][f] = __builtin_amdgcn_mfma_f32_16x16x32_f16(af[m], bf[f], kacc[m][f], 0, 0, 0);
    }
    __syncthreads();
#pragma unroll
    for (int it = 0; it < 4; ++it) {
      const int seg = wv * 4 + it;
      gload16(wh + (size_t)(512 + seg * 8 + lr) * NC + c0 + ssrc, Bt + seg * 512);
    }
    __syncthreads();
#pragma unroll
    for (int kk = 0; kk < 2; ++kk) {
      const int ku = kk * 4 + lg;
      f16x8 af[2], bf[4];
#pragma unroll
      for (int m = 0; m < 2; ++m)
        af[m] = *(const f16x8*)(Xt + swz(ng * 32 + m * 16 + l15, ku));
#pragma unroll
      for (int f = 0; f < 4; ++f)
        bf[f] = *(const f16x8*)(Bt + swz(cg * 64 + f * 16 + l15, ku));
#pragma unroll
      for (int m = 0; m < 2; ++m)
#pragma unroll
        for (int f = 0; f < 4; ++f)
          vacc[m][f] = __builtin_amdgcn_mfma_f32_16x16x32_f16(af[m], bf[f], vacc[m][f], 0, 0, 0);
    }
  }
  float pkv[4] = {0.f, 0.f, 0.f, 0.f}, pden[4] = {0.f, 0.f, 0.f, 0.f};
#pragma unroll
  for (int f = 0; f < 4; ++f)
#pragma unroll
    for (int m = 0; m < 2; ++m)
#pragma unroll
      for (int j = 0; j < 4; ++j) {
        const float kk = elu1(kacc[m][f][j]);
        pkv[f] += kk * vacc[m][f][j];
        pden[f] += kk;
      }
#pragma unroll
  for (int f = 0; f < 4; ++f) {
    pkv[f] += __shfl_xor(pkv[f], 16, 64);
    pkv[f] += __shfl_xor(pkv[f], 32, 64);
    pden[f] += __shfl_xor(pden[f], 16, 64);
    pden[f] += __shfl_xor(pden[f], 32, 64);
  }
  if (lane < 16) {
#pragma unroll
    for (int f = 0; f < 4; ++f) {
      const int c = cg * 64 + f * 16 + lane;
      atomicAdd(&kv[b * NC + c], pkv[f]);
      atomicAdd(&den[b * NC + c], pden[f]);
    }
  }
}

// Fused: qT = Wq . xhT; q' = elu1(qT)*s*1024 -> Q-LDS; out = wouth . Q; LN.
// 256 threads = 4 waves. Grid (64 n-tiles, 16 b).
__global__ __launch_bounds__(256) void k_fused2(const f16* __restrict__ xh,
                                                const f16* __restrict__ wh,
                                                const f16* __restrict__ wouth,
                                                const float* __restrict__ kv,
                                                const float* __restrict__ den,
                                                const float* __restrict__ gamma,
                                                const float* __restrict__ beta,
                                                float* __restrict__ out) {
  __shared__ __align__(16) f16 Xt[64 * 64];    // 8 KB
  __shared__ __align__(16) f16 Wt[256 * 64];   // 32 KB (Wq, then wouth)
  __shared__ __align__(16) f16 Q[64 * 264];    // 33.8 KB, padded
  __shared__ float s1024[256];
  __shared__ float red1[4][64], red2[4][64];
  __shared__ float smu[64], srs[64];
  const int b = blockIdx.y;
  const int n0 = blockIdx.x * 64;
  const int tid = threadIdx.x;
  const int lane = tid & 63;
  const int wv = tid >> 6;          // 0..3
  const int l15 = lane & 15, lg = lane >> 4;
  const int lr = lane >> 3;
  const int ssrc = ((lane & 7) ^ lr) * 8;

  s1024[tid] = kv[b * NC + tid] / fmaxf(den[b * NC + tid], 1e-6f) * 1024.0f;

  f32x4 acc[4][4] = {};   // [m = c-frag][f = n-frag]

  for (int ks = 0; ks < 4; ++ks) {
    const int c0 = ks * 64;
    __syncthreads();
#pragma unroll
    for (int it = 0; it < 2; ++it) {
      const int seg = wv * 2 + it;
      gload16(xh + ((size_t)(b * NN + n0 + seg * 8 + lr)) * NC + c0 + ssrc, Xt + seg * 512);
    }
#pragma unroll
    for (int it = 0; it < 8; ++it) {
      const int seg = wv * 8 + it;
      gload16(wh + (size_t)(seg * 8 + lr) * NC + c0 + ssrc, Wt + seg * 512);
    }
    __syncthreads();
#pragma unroll
    for (int kk = 0; kk < 2; ++kk) {
      const int ku = kk * 4 + lg;
      f16x8 af[4], bf[4];
#pragma unroll
      for (int m = 0; m < 4; ++m)
        af[m] = *(const f16x8*)(Wt + swz(wv * 64 + m * 16 + l15, ku));
#pragma unroll
      for (int f = 0; f < 4; ++f)
        bf[f] = *(const f16x8*)(Xt + swz(f * 16 + l15, ku));
#pragma unroll
      for (int m = 0; m < 4; ++m)
#pragma unroll
        for (int f = 0; f < 4; ++f)
          acc[m][f] = __builtin_amdgcn_mfma_f32_16x16x32_f16(af[m], bf[f], acc[m][f], 0, 0, 0);
    }
  }

  // q epilogue: Q[n][c] = elu1(qT) * s1024[c] (row-wise b64 writes)
#pragma unroll
  for (int m = 0; m < 4; ++m) {
    const int cq = wv * 64 + m * 16 + lg * 4;
#pragma unroll
    for (int f = 0; f < 4; ++f) {
      const int n = f * 16 + l15;
      f16x4v h;
#pragma unroll
      for (int j = 0; j < 4; ++j)
        h[j] = (f16)(elu1(acc[m][f][j]) * s1024[cq + j]);
      *reinterpret_cast<f16x4v*>(Q + n * 264 + cq) = h;
    }
  }

  f32x4 acc2[4][4] = {};  // [m = o-frag][f = n-frag]
  for (int ks = 0; ks < 4; ++ks) {
    const int c0 = ks * 64;
    __syncthreads();   // 1st iter also publishes Q
#pragma unroll
    for (int it = 0; it < 8; ++it) {
      const int seg = wv * 8 + it;
      gload16(wouth + (size_t)(seg * 8 + lr) * NC + c0 + ssrc, Wt + seg * 512);
    }
    __syncthreads();
#pragma unroll
    for (int kk = 0; kk < 2; ++kk) {
      const int ku = kk * 4 + lg;
      const int kb = c0 + kk * 32 + lg * 8;
      f16x8 af[4], bf[4];
#pragma unroll
      for (int m = 0; m < 4; ++m)
        af[m] = *(const f16x8*)(Wt + swz(wv * 64 + m * 16 + l15, ku));
#pragma unroll
      for (int f = 0; f < 4; ++f)
        bf[f] = *(const f16x8*)(Q + (f * 16 + l15) * 264 + kb);
#pragma unroll
      for (int m = 0; m < 4; ++m)
#pragma unroll
        for (int f = 0; f < 4; ++f)
          acc2[m][f] = __builtin_amdgcn_mfma_f32_16x16x32_f16(af[m], bf[f], acc2[m][f], 0, 0, 0);
    }
  }

  // LayerNorm over o (256) per column n
  float s1[4] = {0, 0, 0, 0}, s2[4] = {0, 0, 0, 0};
#pragma unroll
  for (int f = 0; f < 4; ++f)
#pragma unroll
    for (int m = 0; m < 4; ++m)
#pragma unroll
      for (int j = 0; j < 4; ++j) {
        const float v = acc2[m][f][j];
        s1[f] += v;
        s2[f] += v * v;
      }
#pragma unroll
  for (int f = 0; f < 4; ++f) {
    s1[f] += __shfl_xor(s1[f], 16, 64);
    s1[f] += __shfl_xor(s1[f], 32, 64);
    s2[f] += __shfl_xor(s2[f], 16, 64);
    s2[f] += __shfl_xor(s2[f], 32, 64);
  }
  if (lane < 16) {
#pragma unroll
    for (int f = 0; f < 4; ++f) {
      red1[wv][f * 16 + lane] = s1[f];
      red2[wv][f * 16 + lane] = s2[f];
    }
  }
  __syncthreads();
  if (tid < 64) {
    const float a1 = red1[0][tid] + red1[1][tid] + red1[2][tid] + red1[3][tid];
    const float a2 = red2[0][tid] + red2[1][tid] + red2[2][tid] + red2[3][tid];
    const float mu = a1 * (IOSCALE / 256.f);
    const float e2 = a2 * (IOSCALE * IOSCALE / 256.f);
    smu[tid] = mu;
    srs[tid] = rsqrtf(e2 - mu * mu + LN_EPS);
  }
  __syncthreads();
#pragma unroll
  for (int m = 0; m < 4; ++m) {
    const int ob = wv * 64 + m * 16 + lg * 4;
#pragma unroll
    for (int j = 0; j < 4; ++j) {
      const int o = ob + j;
      const float g = gamma[o], be = beta[o];
#pragma unroll
      for (int f = 0; f < 4; ++f) {
        const int col = f * 16 + l15;
        const float v = acc2[m][f][j] * IOSCALE;
        out[((size_t)(b * NC + o)) * NN + n0 + col] = (v - smu[col]) * srs[col] * g + be;
      }
    }
  }
}

extern "C" void kernel_launch(void* const* d_in, const int* in_sizes, int n_in,
                              void* d_out, int out_size, void* d_ws, size_t ws_size,
                              hipStream_t stream) {
  const float* x = (const float*)d_in[0];
  const float* w_qkv = (const float*)d_in[1];
  const float* w_out = (const float*)d_in[2];
  const float* ln_g = (const float*)d_in[3];
  const float* ln_b = (const float*)d_in[4];
  float* out = (float*)d_out;

  char* wsb = (char*)d_ws;
  const size_t OFF_WH = 0;                        // 768*256*2 = 393216
  const size_t OFF_WOUTH = 393216;                // 256*256*2 = 131072
  const size_t OFF_XH = OFF_WOUTH + 131072;       // 32 MiB
  const size_t OFF_KV = OFF_XH + 33554432;        // 16 KiB
  const size_t OFF_DEN = OFF_KV + 16384;          // 16 KiB

  f16* wh = (f16*)(wsb + OFF_WH);
  f16* wouth = (f16*)(wsb + OFF_WOUTH);
  f16* xh = (f16*)(wsb + OFF_XH);
  float* kv = (float*)(wsb + OFF_KV);
  float* den = (float*)(wsb + OFF_DEN);

  k_init<<<768, 256, 0, stream>>>(w_qkv, w_out, wh, wouth, kv);
  k_transpose<<<dim3(64, 4, 16), 256, 0, stream>>>(x, xh);
  k_kv<<<dim3(64, 16), 512, 0, stream>>>(xh, wh, kv, den);
  k_fused2<<<dim3(64, 16), 256, 0, stream>>>(xh, wh, wouth, kv, den, ln_g, ln_b, out);
}